// Round 1
// baseline (935.468 us; speedup 1.0000x reference)
//
#include <hip/hip_runtime.h>
#include <hip/hip_bf16.h>
#include <stdint.h>

#define C_   192
#define H_   256
#define W_   256
#define HW_  65536
#define CHW  12582912
#define NH_  6
#define HID_ 384

typedef __attribute__((ext_vector_type(8))) __bf16 bf16x8;
typedef __attribute__((ext_vector_type(4))) float  fx4;

__device__ __forceinline__ uint16_t f2bf(float f) {
  uint32_t u = __builtin_bit_cast(uint32_t, f);
  u += 0x7fffu + ((u >> 16) & 1u);
  return (uint16_t)(u >> 16);
}
__device__ __forceinline__ float bf2f(uint16_t h) {
  uint32_t u = ((uint32_t)h) << 16;
  return __builtin_bit_cast(float, u);
}
__device__ __forceinline__ uint32_t pk2(float a, float b) {
  return (uint32_t)f2bf(a) | ((uint32_t)f2bf(b) << 16);
}
__device__ __forceinline__ bf16x8 ld8(const uint16_t* p) {
  uint4 v = *reinterpret_cast<const uint4*>(p);
  return __builtin_bit_cast(bf16x8, v);
}
__device__ __forceinline__ fx4 mfma16(bf16x8 a, bf16x8 b, fx4 c) {
  return __builtin_amdgcn_mfma_f32_16x16x32_bf16(a, b, c, 0, 0, 0);
}

// ---------------- K0: weight prep (transpose to bf16 B-fragment layout) ----------------
__global__ __launch_bounds__(256) void prep_kernel(
    const float* __restrict__ qkv_w, const float* __restrict__ proj_w,
    const float* __restrict__ fc1_w, const float* __restrict__ fc2_w,
    const float* __restrict__ rpb,
    uint16_t* __restrict__ qkv_wt, uint16_t* __restrict__ proj_wt,
    uint16_t* __restrict__ fc1_wt, uint16_t* __restrict__ fc2_wt,
    float* __restrict__ rpbb) {
  int tid = blockIdx.x * 256 + threadIdx.x;
  if (tid < 576 * 192) {                       // qkv_wt[f][k] = qkv_w[k][f]
    int f = tid / 192, k = tid % 192;
    qkv_wt[tid] = f2bf(qkv_w[k * 576 + f]);
  }
  int t1 = tid - 576 * 192;
  if (t1 >= 0 && t1 < 192 * 192) {             // proj_wt[f][k]
    int f = t1 / 192, k = t1 % 192;
    proj_wt[t1] = f2bf(proj_w[k * 192 + f]);
  }
  int t2 = t1 - 192 * 192;
  if (t2 >= 0 && t2 < 384 * 192) {             // fc1_wt[f][k]
    int f = t2 / 192, k = t2 % 192;
    fc1_wt[t2] = f2bf(fc1_w[k * 384 + f]);
  }
  int t3 = t2 - 384 * 192;
  if (t3 >= 0 && t3 < 192 * 384) {             // fc2_wt[o][k]
    int f = t3 / 384, k = t3 % 384;
    fc2_wt[t3] = f2bf(fc2_w[k * 192 + f]);
  }
  int t4 = t3 - 192 * 384;
  if (t4 >= 0 && t4 < 6 * 64 * 64) {           // rpbb[h][n][m]
    int h = t4 / 4096, nm = t4 % 4096, n = nm / 64, m = nm % 64;
    int yn = n >> 3, xn = n & 7, ym = m >> 3, xm = m & 7;
    int idx = (yn - ym + 7) * 15 + (xn - xm + 7);
    rpbb[t4] = rpb[idx * NH_ + h];
  }
}

// ---------------- K1a: LN1 stats (mu, rsig per pixel) ----------------
__global__ __launch_bounds__(256) void ln1_stats(const float* __restrict__ x,
                                                 float* __restrict__ mu,
                                                 float* __restrict__ rsig) {
  int t = blockIdx.x * 256 + threadIdx.x;   // (b,hw)
  int b = t >> 16, hw = t & 65535;
  const float* xp = x + (size_t)b * CHW + hw;
  float s = 0.f, sq = 0.f;
#pragma unroll 8
  for (int c = 0; c < C_; c++) {
    float v = xp[(size_t)c * HW_];
    s += v; sq += v * v;
  }
  float m = s * (1.0f / C_);
  float var = sq * (1.0f / C_) - m * m;
  mu[t] = m;
  rsig[t] = rsqrtf(var + 1e-6f);
}

// ---------------- K1b: apply LN1 + roll-reinterpret shuffle + transpose -> token-major bf16 --
__global__ __launch_bounds__(256) void ln1_apply_kernel(
    const float* __restrict__ x, const float* __restrict__ mu, const float* __restrict__ rsig,
    const float* __restrict__ n1w, const float* __restrict__ n1b,
    uint16_t* __restrict__ y_tok) {
  __shared__ __attribute__((aligned(16))) uint16_t tile[192 * 66];
  int wg = blockIdx.x;
  int b = wg >> 10, hw0 = (wg & 1023) << 6;
  int t = threadIdx.x;
  const float* xb = x + (size_t)b * CHW;
  const float* mub = mu + b * HW_;
  const float* rsb = rsig + b * HW_;
#pragma unroll 4
  for (int it = 0; it < 48; it++) {
    int id = it * 256 + t;
    int ca = id >> 6, pp = id & 63;
    int g = ca * 65536 + hw0 + pp;
    int h2 = g / 49152;
    int r = g - h2 * 49152;
    int w2 = r / 192;
    int c2 = r - w2 * 192;
    int f = ((h2 + 4) & 255) * 49152 + ((w2 + 4) & 255) * 192 + c2;
    int cnat = f >> 16;
    int hwn = f & 65535;
    float v = (xb[f] - mub[hwn]) * rsb[hwn] * n1w[cnat] + n1b[cnat];
    tile[ca * 66 + pp] = f2bf(v);
  }
  __syncthreads();
  uint16_t* yb = y_tok + ((size_t)(b * HW_ + hw0)) * C_;
#pragma unroll 4
  for (int it = 0; it < 48; it++) {
    int id = it * 256 + t;
    int pp = id / 192, ca = id - pp * 192;
    yb[id] = tile[ca * 66 + pp];
  }
}

// ---------------- K2: fused window attention (QKV + softmax(QK^T+bias+mask) V + proj) -------
__global__ __launch_bounds__(256, 2) void attn_kernel(
    const uint16_t* __restrict__ y_tok, const uint16_t* __restrict__ qkv_wt,
    const float* __restrict__ qkv_b, const uint16_t* __restrict__ proj_wt,
    const float* __restrict__ proj_b, const float* __restrict__ rpbb,
    uint16_t* __restrict__ y_attn) {
  __shared__ __attribute__((aligned(16))) uint16_t Qs[64 * 200]; // Q, later O
  __shared__ __attribute__((aligned(16))) uint16_t Ks[64 * 200];
  __shared__ __attribute__((aligned(16))) uint16_t VT[32 * 72];
  __shared__ __attribute__((aligned(16))) uint16_t Ps[64 * 72];
  const int wg = blockIdx.x;
  const int b = wg >> 10, wid = wg & 1023;
  const int wh = wid >> 5, ww = wid & 31;
  const int t = threadIdx.x;
  const int w = t >> 6, l = t & 63;
  const int lane16 = l & 15, quad = l >> 4;

  // A fragments straight from global (token rows are contiguous 384B)
  const int tokA = w * 16 + lane16;
  const int hA = wh * 8 + (tokA >> 3), wA = ww * 8 + (tokA & 7);
  const uint16_t* aptr = y_tok + ((size_t)(b * HW_ + hA * W_ + wA)) * C_ + quad * 8;
  bf16x8 afr[6];
#pragma unroll
  for (int ks = 0; ks < 6; ks++) afr[ks] = ld8(aptr + ks * 32);

  // ---- QKV GEMM: 36 n-tiles of 16 features ----
  uint32_t vpack[12][2];
  const float scale = 0.17677669529663687f;
  const int trow = w * 16 + quad * 4;
#pragma unroll 2
  for (int nt = 0; nt < 36; nt++) {
    const uint16_t* bp = qkv_wt + (nt * 16 + lane16) * C_ + quad * 8;
    fx4 acc = {0.f, 0.f, 0.f, 0.f};
#pragma unroll
    for (int ks = 0; ks < 6; ks++) acc = mfma16(afr[ks], ld8(bp + ks * 32), acc);
    const int f = nt * 16 + lane16;
    const float bias = qkv_b[f];
    if (nt < 12) {
#pragma unroll
      for (int r = 0; r < 4; r++) Qs[(trow + r) * 200 + f] = f2bf((acc[r] + bias) * scale);
    } else if (nt < 24) {
#pragma unroll
      for (int r = 0; r < 4; r++) Ks[(trow + r) * 200 + (f - 192)] = f2bf(acc[r] + bias);
    } else {
      const int nv = nt - 24;
      vpack[nv][0] = pk2(acc[0] + bias, acc[1] + bias);
      vpack[nv][1] = pk2(acc[2] + bias, acc[3] + bias);
    }
  }

  const bool whe = (wh == 31), wwe = (ww == 31);

  for (int h = 0; h < 6; h++) {
    __syncthreads();  // K ready (h=0) / prev-head PV reads of VT done (h>0)
#pragma unroll
    for (int nvb = 0; nvb < 2; nvb++) {
      const int nv = 2 * h + nvb;
      uint2 vv; vv.x = vpack[nv][0]; vv.y = vpack[nv][1];
      *reinterpret_cast<uint2*>(&VT[(nvb * 16 + lane16) * 72 + w * 16 + quad * 4]) = vv;
    }
    __syncthreads();

    // S = Q K^T (one K=32 step per head)
    const bf16x8 qa = ld8(&Qs[(w * 16 + lane16) * 200 + h * 32 + quad * 8]);
    fx4 sacc[4];
#pragma unroll
    for (int nt = 0; nt < 4; nt++) {
      const bf16x8 kb = ld8(&Ks[(nt * 16 + lane16) * 200 + h * 32 + quad * 8]);
      fx4 z = {0.f, 0.f, 0.f, 0.f};
      sacc[nt] = mfma16(qa, kb, z);
    }
    // bias + shifted-window mask
    const float* rb = rpbb + h * 4096;
#pragma unroll
    for (int nt = 0; nt < 4; nt++) {
      const int ct = nt * 16 + lane16;
      const bool rbc = whe && ((ct >> 3) >= 4);
      const bool cbc = wwe && ((ct & 7) >= 4);
#pragma unroll
      for (int r = 0; r < 4; r++) {
        const int rt = trow + r;
        const bool rbr = whe && ((rt >> 3) >= 4);
        const bool cbr = wwe && ((rt & 7) >= 4);
        float v = sacc[nt][r] + rb[rt * 64 + ct];
        if (rbr != rbc || cbr != cbc) v -= 100.f;
        sacc[nt][r] = v;
      }
    }
    // softmax across the 64 columns (rows live in 16 lanes)
    float sm[4];
#pragma unroll
    for (int r = 0; r < 4; r++) {
      float m = fmaxf(fmaxf(sacc[0][r], sacc[1][r]), fmaxf(sacc[2][r], sacc[3][r]));
      m = fmaxf(m, __shfl_xor(m, 1));
      m = fmaxf(m, __shfl_xor(m, 2));
      m = fmaxf(m, __shfl_xor(m, 4));
      m = fmaxf(m, __shfl_xor(m, 8));
      float s0 = 0.f;
#pragma unroll
      for (int nt = 0; nt < 4; nt++) {
        float e = exp2f((sacc[nt][r] - m) * 1.4426950408889634f);
        sacc[nt][r] = e; s0 += e;
      }
      s0 += __shfl_xor(s0, 1);
      s0 += __shfl_xor(s0, 2);
      s0 += __shfl_xor(s0, 4);
      s0 += __shfl_xor(s0, 8);
      sm[r] = s0;
    }
    // P -> LDS (wave-private rows), layout transform C->A
#pragma unroll
    for (int nt = 0; nt < 4; nt++)
#pragma unroll
      for (int r = 0; r < 4; r++)
        Ps[(trow + r) * 72 + nt * 16 + lane16] = f2bf(sacc[nt][r]);
    // O_h = P V
    fx4 o0 = {0.f, 0.f, 0.f, 0.f}, o1 = {0.f, 0.f, 0.f, 0.f};
#pragma unroll
    for (int ks2 = 0; ks2 < 2; ks2++) {
      const bf16x8 pa = ld8(&Ps[(w * 16 + lane16) * 72 + ks2 * 32 + quad * 8]);
      const bf16x8 v0 = ld8(&VT[(lane16) * 72 + ks2 * 32 + quad * 8]);
      const bf16x8 v1 = ld8(&VT[(16 + lane16) * 72 + ks2 * 32 + quad * 8]);
      o0 = mfma16(pa, v0, o0);
      o1 = mfma16(pa, v1, o1);
    }
    // scale rows by 1/sum, write O into Qs cols [h*32, h*32+32) (already consumed)
#pragma unroll
    for (int r = 0; r < 4; r++) {
      const float inv = 1.0f / sm[r];
      Qs[(trow + r) * 200 + h * 32 + lane16] = f2bf(o0[r] * inv);
      Qs[(trow + r) * 200 + h * 32 + 16 + lane16] = f2bf(o1[r] * inv);
    }
  }

  // ---- proj GEMM: O(64x192) @ Wproj(192x192), coalesced token-major store ----
  bf16x8 ofr[6];
#pragma unroll
  for (int ks = 0; ks < 6; ks++)
    ofr[ks] = ld8(&Qs[(w * 16 + lane16) * 200 + ks * 32 + quad * 8]);
  size_t obase[4];
#pragma unroll
  for (int r = 0; r < 4; r++) {
    const int tok = trow + r;
    const int hw = (wh * 8 + (tok >> 3)) * W_ + ww * 8 + (tok & 7);
    obase[r] = ((size_t)(b * HW_ + hw)) * C_;
  }
#pragma unroll 2
  for (int nt = 0; nt < 12; nt++) {
    const uint16_t* bp = proj_wt + (nt * 16 + lane16) * C_ + quad * 8;
    fx4 acc = {0.f, 0.f, 0.f, 0.f};
#pragma unroll
    for (int ks = 0; ks < 6; ks++) acc = mfma16(ofr[ks], ld8(bp + ks * 32), acc);
    const float pb = proj_b[nt * 16 + lane16];
#pragma unroll
    for (int r = 0; r < 4; r++)
      y_attn[obase[r] + nt * 16 + lane16] = f2bf(acc[r] + pb);
  }
}

// ---------------- K3a: per-slice channel sums of y_attn ----------------
__global__ __launch_bounds__(256) void gap_partial(const uint16_t* __restrict__ y_attn,
                                                   float* __restrict__ part) {
  int wg = blockIdx.x;           // 256: b = wg>>7, slice = wg&127 (512 tokens)
  int b = wg >> 7, sl = wg & 127;
  int t = threadIdx.x;
  if (t < 192) {
    size_t base = ((size_t)(b * HW_ + sl * 512)) * C_ + t;
    float s = 0.f;
#pragma unroll 8
    for (int r = 0; r < 512; r++) s += bf2f(y_attn[base + (size_t)r * C_]);
    part[wg * 192 + t] = s;
  }
}

// ---------------- K3b: gap -> channel-attention scale s[b][o] ----------------
__global__ __launch_bounds__(256) void ca_s_kernel(const float* __restrict__ part,
                                                   const float* __restrict__ ca_w,
                                                   const float* __restrict__ ca_b,
                                                   float* __restrict__ sbuf) {
  int b = blockIdx.x;
  int t = threadIdx.x;
  __shared__ float gap[192];
  if (t < 192) {
    float s = 0.f;
    for (int i = 0; i < 128; i++) s += part[(b * 128 + i) * 192 + t];
    gap[t] = s * (1.0f / 65536.0f);
  }
  __syncthreads();
  if (t < 192) {
    float s = ca_b[t];
#pragma unroll 4
    for (int c = 0; c < 192; c++) s += gap[c] * ca_w[t * 192 + c];
    sbuf[b * 192 + t] = s;
  }
}

// ---------------- K4: x_new = x + s*y_attn ; LN2 -> token-major bf16 ----------------
__global__ __launch_bounds__(256, 3) void resid_ln2(
    const float* __restrict__ x, const uint16_t* __restrict__ y_attn,
    const float* __restrict__ sbuf, const float* __restrict__ n2w,
    const float* __restrict__ n2b, float* __restrict__ x_new,
    uint16_t* __restrict__ t2) {
  __shared__ __attribute__((aligned(16))) float tile[192 * 66];
  __shared__ float red[512];
  __shared__ float mus[128];
  int wg = blockIdx.x;
  int b = wg >> 10, hw0 = (wg & 1023) << 6;
  int t = threadIdx.x;
  // load x tile (BCHW coalesced)
#pragma unroll 4
  for (int it = 0; it < 48; it++) {
    int id = it * 256 + t;
    int c = id >> 6, p = id & 63;
    tile[c * 66 + p] = x[(size_t)b * CHW + (size_t)c * HW_ + hw0 + p];
  }
  __syncthreads();
  // add s[c] * y_attn (token-major coalesced)
#pragma unroll 4
  for (int it = 0; it < 48; it++) {
    int id = it * 256 + t;
    int p = id / 192, c = id - p * 192;
    float y = bf2f(y_attn[((size_t)(b * HW_ + hw0 + p)) * C_ + c]);
    tile[c * 66 + p] += sbuf[b * 192 + c] * y;
  }
  __syncthreads();
  // LN2 stats per pixel
  {
    int p = t & 63, g = t >> 6;
    float s = 0.f, sq = 0.f;
    for (int c = g * 48; c < g * 48 + 48; c++) {
      float v = tile[c * 66 + p];
      s += v; sq += v * v;
    }
    red[g * 64 + p] = s;
    red[256 + g * 64 + p] = sq;
  }
  __syncthreads();
  if (t < 64) {
    float ss = red[t] + red[64 + t] + red[128 + t] + red[192 + t];
    float qq = red[256 + t] + red[320 + t] + red[384 + t] + red[448 + t];
    float m = ss * (1.0f / C_);
    float var = qq * (1.0f / C_) - m * m;
    mus[t] = m;
    mus[64 + t] = rsqrtf(var + 1e-6f);
  }
  __syncthreads();
  // write x_new (BCHW) and t2 (token-major bf16)
#pragma unroll 4
  for (int it = 0; it < 48; it++) {
    int id = it * 256 + t;
    int c = id >> 6, p = id & 63;
    x_new[(size_t)b * CHW + (size_t)c * HW_ + hw0 + p] = tile[c * 66 + p];
  }
#pragma unroll 4
  for (int it = 0; it < 48; it++) {
    int id = it * 256 + t;
    int p = id / 192, c = id - p * 192;
    float v = (tile[c * 66 + p] - mus[p]) * mus[64 + p] * n2w[c] + n2b[c];
    t2[((size_t)(b * HW_ + hw0 + p)) * C_ + c] = f2bf(v);
  }
}

// ---------------- K6: MLP (GEMM1+GELU+GEMM2) + final residual, BCHW out ----------------
__global__ __launch_bounds__(256, 2) void mlp_kernel(
    const uint16_t* __restrict__ t2, const uint16_t* __restrict__ fc1_wt,
    const float* __restrict__ fc1_b, const uint16_t* __restrict__ fc2_wt,
    const float* __restrict__ fc2_b, const float* __restrict__ x_new,
    float* __restrict__ out) {
  __shared__ __attribute__((aligned(16))) char smem[64 * 392 * 2];  // hbuf, later obuf
  uint16_t* hbuf = (uint16_t*)smem;          // [64][392]
  uint16_t* obuf = (uint16_t*)smem;          // [192][68] (aliased after barrier)
  int wg = blockIdx.x;
  int b = wg >> 10, hw0 = (wg & 1023) << 6;
  int t = threadIdx.x;
  int w = t >> 6, l = t & 63;
  int lane16 = l & 15, quad = l >> 4;
  const int trow = w * 16 + quad * 4;

  // A frags direct from global token-major t2
  const uint16_t* aptr = t2 + ((size_t)(b * HW_ + hw0 + w * 16 + lane16)) * C_ + quad * 8;
  bf16x8 afr[6];
#pragma unroll
  for (int ks = 0; ks < 6; ks++) afr[ks] = ld8(aptr + ks * 32);

  // GEMM1 + exact GELU -> hbuf
#pragma unroll 2
  for (int nt = 0; nt < 24; nt++) {
    const uint16_t* bp = fc1_wt + (nt * 16 + lane16) * C_ + quad * 8;
    fx4 acc = {0.f, 0.f, 0.f, 0.f};
#pragma unroll
    for (int ks = 0; ks < 6; ks++) acc = mfma16(afr[ks], ld8(bp + ks * 32), acc);
    const float bias = fc1_b[nt * 16 + lane16];
#pragma unroll
    for (int r = 0; r < 4; r++) {
      float v = acc[r] + bias;
      float ge = 0.5f * v * (1.0f + erff(v * 0.7071067811865476f));
      hbuf[(trow + r) * 392 + nt * 16 + lane16] = f2bf(ge);
    }
  }
  // load hidden A-frags (wave-private rows, in-order DS)
  bf16x8 ha[12];
#pragma unroll
  for (int ks = 0; ks < 12; ks++)
    ha[ks] = ld8(&hbuf[(w * 16 + lane16) * 392 + ks * 32 + quad * 8]);
  __syncthreads();   // all waves done with hbuf; obuf may now alias it

  // GEMM2 -> obuf transposed [c][tok]
#pragma unroll 2
  for (int nt = 0; nt < 12; nt++) {
    const uint16_t* bp = fc2_wt + (nt * 16 + lane16) * HID_ + quad * 8;
    fx4 acc = {0.f, 0.f, 0.f, 0.f};
#pragma unroll
    for (int ks = 0; ks < 12; ks++) acc = mfma16(ha[ks], ld8(bp + ks * 32), acc);
    const float bias = fc2_b[nt * 16 + lane16];
    uint2 vv;
    vv.x = pk2(acc[0] + bias, acc[1] + bias);
    vv.y = pk2(acc[2] + bias, acc[3] + bias);
    *reinterpret_cast<uint2*>(&obuf[(nt * 16 + lane16) * 68 + w * 16 + quad * 4]) = vv;
  }
  __syncthreads();
  // out = x_new + y2^T (BCHW coalesced)
#pragma unroll 4
  for (int it = 0; it < 48; it++) {
    int id = it * 256 + t;
    int c = id >> 6, p = id & 63;
    size_t gi = (size_t)b * CHW + (size_t)c * HW_ + hw0 + p;
    out[gi] = x_new[gi] + bf2f(obuf[c * 68 + p]);
  }
}

extern "C" void kernel_launch(void* const* d_in, const int* in_sizes, int n_in,
                              void* d_out, int out_size, void* d_ws, size_t ws_size,
                              hipStream_t stream) {
  const float* x      = (const float*)d_in[0];
  const float* n1w    = (const float*)d_in[1];
  const float* n1b    = (const float*)d_in[2];
  const float* qkv_w  = (const float*)d_in[3];
  const float* qkv_b  = (const float*)d_in[4];
  const float* proj_w = (const float*)d_in[5];
  const float* proj_b = (const float*)d_in[6];
  const float* rpb    = (const float*)d_in[7];
  const float* ca_w   = (const float*)d_in[8];
  const float* ca_b   = (const float*)d_in[9];
  const float* n2w    = (const float*)d_in[10];
  const float* n2b    = (const float*)d_in[11];
  const float* fc1_w  = (const float*)d_in[12];
  const float* fc1_b  = (const float*)d_in[13];
  const float* fc2_w  = (const float*)d_in[14];
  const float* fc2_b  = (const float*)d_in[15];
  float* out = (float*)d_out;

  char* ws = (char*)d_ws;
  uint16_t* y_tok   = (uint16_t*)(ws + 0);           // 50331648 B (aliased by t2)
  uint16_t* y_attn  = (uint16_t*)(ws + 50331648);    // 50331648 B
  float*    x_new   = (float*)   (ws + 100663296);   // 100663296 B
  uint16_t* t2      = y_tok;                         // alias (y_tok dead after attn)
  float*    mu      = (float*)   (ws + 201326592);   // 524288 B
  float*    rsig    = (float*)   (ws + 201850880);   // 524288 B
  uint16_t* qkv_wt  = (uint16_t*)(ws + 202375168);   // 221184 B
  uint16_t* proj_wt = (uint16_t*)(ws + 202596352);   // 73728 B
  uint16_t* fc1_wt  = (uint16_t*)(ws + 202670080);   // 147456 B
  uint16_t* fc2_wt  = (uint16_t*)(ws + 202817536);   // 147456 B
  float*    rpbb    = (float*)   (ws + 202964992);   // 98304 B
  float*    part    = (float*)   (ws + 203063296);   // 196608 B
  float*    sbuf    = (float*)   (ws + 203259904);   // 1536 B

  hipLaunchKernelGGL(prep_kernel, dim3(1248), dim3(256), 0, stream,
                     qkv_w, proj_w, fc1_w, fc2_w, rpb, qkv_wt, proj_wt, fc1_wt, fc2_wt, rpbb);
  hipLaunchKernelGGL(ln1_stats, dim3(512), dim3(256), 0, stream, x, mu, rsig);
  hipLaunchKernelGGL(ln1_apply_kernel, dim3(2048), dim3(256), 0, stream,
                     x, mu, rsig, n1w, n1b, y_tok);
  hipLaunchKernelGGL(attn_kernel, dim3(2048), dim3(256), 0, stream,
                     y_tok, qkv_wt, qkv_b, proj_wt, proj_b, rpbb, y_attn);
  hipLaunchKernelGGL(gap_partial, dim3(256), dim3(256), 0, stream, y_attn, part);
  hipLaunchKernelGGL(ca_s_kernel, dim3(2), dim3(256), 0, stream, part, ca_w, ca_b, sbuf);
  hipLaunchKernelGGL(resid_ln2, dim3(2048), dim3(256), 0, stream,
                     x, y_attn, sbuf, n2w, n2b, x_new, t2);
  hipLaunchKernelGGL(mlp_kernel, dim3(2048), dim3(256), 0, stream,
                     t2, fc1_wt, fc1_b, fc2_wt, fc2_b, x_new, out);
}

// Round 2
// 575.220 us; speedup vs baseline: 1.6263x; 1.6263x over previous
//
#include <hip/hip_runtime.h>
#include <hip/hip_bf16.h>
#include <stdint.h>

#define C_   192
#define H_   256
#define W_   256
#define HW_  65536
#define CHW  12582912
#define NH_  6
#define HID_ 384

typedef __attribute__((ext_vector_type(8))) __bf16 bf16x8;
typedef __attribute__((ext_vector_type(4))) float  fx4;

__device__ __forceinline__ uint16_t f2bf(float f) {
  uint32_t u = __builtin_bit_cast(uint32_t, f);
  u += 0x7fffu + ((u >> 16) & 1u);
  return (uint16_t)(u >> 16);
}
__device__ __forceinline__ float bf2f(uint16_t h) {
  uint32_t u = ((uint32_t)h) << 16;
  return __builtin_bit_cast(float, u);
}
__device__ __forceinline__ uint32_t pk2(float a, float b) {
  return (uint32_t)f2bf(a) | ((uint32_t)f2bf(b) << 16);
}
__device__ __forceinline__ bf16x8 ld8(const uint16_t* p) {
  uint4 v = *reinterpret_cast<const uint4*>(p);
  return __builtin_bit_cast(bf16x8, v);
}
__device__ __forceinline__ fx4 mfma16(bf16x8 a, bf16x8 b, fx4 c) {
  return __builtin_amdgcn_mfma_f32_16x16x32_bf16(a, b, c, 0, 0, 0);
}

// ---------------- K0: weight prep (transpose to bf16 B-fragment layout) ----------------
__global__ __launch_bounds__(256) void prep_kernel(
    const float* __restrict__ qkv_w, const float* __restrict__ proj_w,
    const float* __restrict__ fc1_w, const float* __restrict__ fc2_w,
    const float* __restrict__ rpb,
    uint16_t* __restrict__ qkv_wt, uint16_t* __restrict__ proj_wt,
    uint16_t* __restrict__ fc1_wt, uint16_t* __restrict__ fc2_wt,
    float* __restrict__ rpbb) {
  int tid = blockIdx.x * 256 + threadIdx.x;
  if (tid < 576 * 192) {                       // qkv_wt[f][k] = qkv_w[k][f]
    int f = tid / 192, k = tid % 192;
    qkv_wt[tid] = f2bf(qkv_w[k * 576 + f]);
  }
  int t1 = tid - 576 * 192;
  if (t1 >= 0 && t1 < 192 * 192) {             // proj_wt[f][k]
    int f = t1 / 192, k = t1 % 192;
    proj_wt[t1] = f2bf(proj_w[k * 192 + f]);
  }
  int t2 = t1 - 192 * 192;
  if (t2 >= 0 && t2 < 384 * 192) {             // fc1_wt[f][k]
    int f = t2 / 192, k = t2 % 192;
    fc1_wt[t2] = f2bf(fc1_w[k * 384 + f]);
  }
  int t3 = t2 - 384 * 192;
  if (t3 >= 0 && t3 < 192 * 384) {             // fc2_wt[o][k]
    int f = t3 / 384, k = t3 % 384;
    fc2_wt[t3] = f2bf(fc2_w[k * 192 + f]);
  }
  int t4 = t3 - 192 * 384;
  if (t4 >= 0 && t4 < 6 * 64 * 64) {           // rpbb[h][n][m]
    int h = t4 / 4096, nm = t4 % 4096, n = nm / 64, m = nm % 64;
    int yn = n >> 3, xn = n & 7, ym = m >> 3, xm = m & 7;
    int idx = (yn - ym + 7) * 15 + (xn - xm + 7);
    rpbb[t4] = rpb[idx * NH_ + h];
  }
}

// ---------------- K1a: LN1 stats (mu, rsig per pixel) ----------------
__global__ __launch_bounds__(256) void ln1_stats(const float* __restrict__ x,
                                                 float* __restrict__ mu,
                                                 float* __restrict__ rsig) {
  int t = blockIdx.x * 256 + threadIdx.x;   // (b,hw)
  int b = t >> 16, hw = t & 65535;
  const float* xp = x + (size_t)b * CHW + hw;
  float s = 0.f, sq = 0.f;
#pragma unroll 8
  for (int c = 0; c < C_; c++) {
    float v = xp[(size_t)c * HW_];
    s += v; sq += v * v;
  }
  float m = s * (1.0f / C_);
  float var = sq * (1.0f / C_) - m * m;
  mu[t] = m;
  rsig[t] = rsqrtf(var + 1e-6f);
}

// ---------------- K1b: apply LN1 + roll-reinterpret shuffle + transpose -> token-major bf16 --
__global__ __launch_bounds__(256) void ln1_apply_kernel(
    const float* __restrict__ x, const float* __restrict__ mu, const float* __restrict__ rsig,
    const float* __restrict__ n1w, const float* __restrict__ n1b,
    uint16_t* __restrict__ y_tok) {
  __shared__ __attribute__((aligned(16))) uint16_t tile[192 * 66];
  int wg = blockIdx.x;
  int b = wg >> 10, hw0 = (wg & 1023) << 6;
  int t = threadIdx.x;
  const float* xb = x + (size_t)b * CHW;
  const float* mub = mu + b * HW_;
  const float* rsb = rsig + b * HW_;
#pragma unroll 4
  for (int it = 0; it < 48; it++) {
    int id = it * 256 + t;
    int ca = id >> 6, pp = id & 63;
    int g = ca * 65536 + hw0 + pp;
    int h2 = g / 49152;
    int r = g - h2 * 49152;
    int w2 = r / 192;
    int c2 = r - w2 * 192;
    int f = ((h2 + 4) & 255) * 49152 + ((w2 + 4) & 255) * 192 + c2;
    int cnat = f >> 16;
    int hwn = f & 65535;
    float v = (xb[f] - mub[hwn]) * rsb[hwn] * n1w[cnat] + n1b[cnat];
    tile[ca * 66 + pp] = f2bf(v);
  }
  __syncthreads();
  uint16_t* yb = y_tok + ((size_t)(b * HW_ + hw0)) * C_;
#pragma unroll 4
  for (int it = 0; it < 48; it++) {
    int id = it * 256 + t;
    int pp = id / 192, ca = id - pp * 192;
    yb[id] = tile[ca * 66 + pp];
  }
}

// ---------------- K2: fused window attention (QKV + softmax(QK^T+bias+mask) V + proj) -------
// n-split GEMMs: each wave holds A-frags for all 64 tokens, owns n-tiles nt%4==w.
__global__ __launch_bounds__(256, 2) void attn_kernel(
    const uint16_t* __restrict__ y_tok, const uint16_t* __restrict__ qkv_wt,
    const float* __restrict__ qkv_b, const uint16_t* __restrict__ proj_wt,
    const float* __restrict__ proj_b, const float* __restrict__ rpbb,
    uint16_t* __restrict__ y_attn) {
  __shared__ __attribute__((aligned(16))) uint16_t Qs[64 * 200]; // Q, later O
  __shared__ __attribute__((aligned(16))) uint16_t Ks[64 * 200];
  __shared__ __attribute__((aligned(16))) uint16_t VT[32 * 72];
  __shared__ __attribute__((aligned(16))) uint16_t Ps[64 * 72];
  const int wg = blockIdx.x;
  const int b = wg >> 10, wid = wg & 1023;
  const int wh = wid >> 5, ww = wid & 31;
  const int t = threadIdx.x;
  const int w = t >> 6, l = t & 63;
  const int lane16 = l & 15, quad = l >> 4;
  const int trow = w * 16 + quad * 4;

  // A fragments for ALL 64 tokens (token rows contiguous 384B in y_tok)
  bf16x8 afr[4][6];
#pragma unroll
  for (int m = 0; m < 4; m++) {
    const int tok = m * 16 + lane16;
    const uint16_t* ap = y_tok +
        ((size_t)(b * HW_ + (wh * 8 + (tok >> 3)) * W_ + ww * 8 + (tok & 7))) * C_ + quad * 8;
#pragma unroll
    for (int k = 0; k < 6; k++) afr[m][k] = ld8(ap + k * 32);
  }

  const float scale = 0.17677669529663687f;
  uint32_t vpack[3][4][2];

  // ---- QKV GEMM: wave w owns nt = w + 4j. j 0..2: Q, 3..5: K, 6..8: V ----
#pragma unroll
  for (int j = 0; j < 3; j++) {
    const int nt = w + 4 * j;
    const uint16_t* bp = qkv_wt + (nt * 16 + lane16) * C_ + quad * 8;
    bf16x8 bfr[6];
#pragma unroll
    for (int k = 0; k < 6; k++) bfr[k] = ld8(bp + k * 32);
    fx4 acc[4];
#pragma unroll
    for (int m = 0; m < 4; m++) acc[m] = fx4{0.f, 0.f, 0.f, 0.f};
#pragma unroll
    for (int k = 0; k < 6; k++)
#pragma unroll
      for (int m = 0; m < 4; m++) acc[m] = mfma16(afr[m][k], bfr[k], acc[m]);
    const int f = nt * 16 + lane16;
    const float bias = qkv_b[f];
#pragma unroll
    for (int m = 0; m < 4; m++)
#pragma unroll
      for (int r = 0; r < 4; r++)
        Qs[(m * 16 + quad * 4 + r) * 200 + f] = f2bf((acc[m][r] + bias) * scale);
  }
#pragma unroll
  for (int j = 3; j < 6; j++) {
    const int nt = w + 4 * j;
    const uint16_t* bp = qkv_wt + (nt * 16 + lane16) * C_ + quad * 8;
    bf16x8 bfr[6];
#pragma unroll
    for (int k = 0; k < 6; k++) bfr[k] = ld8(bp + k * 32);
    fx4 acc[4];
#pragma unroll
    for (int m = 0; m < 4; m++) acc[m] = fx4{0.f, 0.f, 0.f, 0.f};
#pragma unroll
    for (int k = 0; k < 6; k++)
#pragma unroll
      for (int m = 0; m < 4; m++) acc[m] = mfma16(afr[m][k], bfr[k], acc[m]);
    const int f = nt * 16 + lane16;
    const float bias = qkv_b[f];
#pragma unroll
    for (int m = 0; m < 4; m++)
#pragma unroll
      for (int r = 0; r < 4; r++)
        Ks[(m * 16 + quad * 4 + r) * 200 + (f - 192)] = f2bf(acc[m][r] + bias);
  }
#pragma unroll
  for (int j = 6; j < 9; j++) {
    const int nt = w + 4 * j;
    const uint16_t* bp = qkv_wt + (nt * 16 + lane16) * C_ + quad * 8;
    bf16x8 bfr[6];
#pragma unroll
    for (int k = 0; k < 6; k++) bfr[k] = ld8(bp + k * 32);
    fx4 acc[4];
#pragma unroll
    for (int m = 0; m < 4; m++) acc[m] = fx4{0.f, 0.f, 0.f, 0.f};
#pragma unroll
    for (int k = 0; k < 6; k++)
#pragma unroll
      for (int m = 0; m < 4; m++) acc[m] = mfma16(afr[m][k], bfr[k], acc[m]);
    const float bias = qkv_b[nt * 16 + lane16];
    const int jv = j - 6;   // owned V-tile vt = w + 4*jv  (vt%4 == w)
#pragma unroll
    for (int m = 0; m < 4; m++) {
      vpack[jv][m][0] = pk2(acc[m][0] + bias, acc[m][1] + bias);
      vpack[jv][m][1] = pk2(acc[m][2] + bias, acc[m][3] + bias);
    }
  }

  const bool whe = (wh == 31), wwe = (ww == 31);

  for (int h = 0; h < 6; h++) {
    __syncthreads();  // Q/K ready (h=0) / prev-head PV reads of VT done (h>0)
    // stage V-tiles 2h, 2h+1 from their owning waves
    {
      const int vt0 = 2 * h, vt1 = 2 * h + 1;
      if (w == (vt0 & 3)) {
        const int jv = vt0 >> 2;
#pragma unroll
        for (int m = 0; m < 4; m++) {
          uint2 vv; vv.x = vpack[jv][m][0]; vv.y = vpack[jv][m][1];
          *reinterpret_cast<uint2*>(&VT[lane16 * 72 + m * 16 + quad * 4]) = vv;
        }
      }
      if (w == (vt1 & 3)) {
        const int jv = vt1 >> 2;
#pragma unroll
        for (int m = 0; m < 4; m++) {
          uint2 vv; vv.x = vpack[jv][m][0]; vv.y = vpack[jv][m][1];
          *reinterpret_cast<uint2*>(&VT[(16 + lane16) * 72 + m * 16 + quad * 4]) = vv;
        }
      }
    }
    __syncthreads();

    // S = Q K^T (one K=32 step per head)
    const bf16x8 qa = ld8(&Qs[(w * 16 + lane16) * 200 + h * 32 + quad * 8]);
    fx4 sacc[4];
#pragma unroll
    for (int nt = 0; nt < 4; nt++) {
      const bf16x8 kb = ld8(&Ks[(nt * 16 + lane16) * 200 + h * 32 + quad * 8]);
      fx4 z = {0.f, 0.f, 0.f, 0.f};
      sacc[nt] = mfma16(qa, kb, z);
    }
    // bias + shifted-window mask
    const float* rb = rpbb + h * 4096;
#pragma unroll
    for (int nt = 0; nt < 4; nt++) {
      const int ct = nt * 16 + lane16;
      const bool rbc = whe && ((ct >> 3) >= 4);
      const bool cbc = wwe && ((ct & 7) >= 4);
#pragma unroll
      for (int r = 0; r < 4; r++) {
        const int rt = trow + r;
        const bool rbr = whe && ((rt >> 3) >= 4);
        const bool cbr = wwe && ((rt & 7) >= 4);
        float v = sacc[nt][r] + rb[rt * 64 + ct];
        if (rbr != rbc || cbr != cbc) v -= 100.f;
        sacc[nt][r] = v;
      }
    }
    // softmax across the 64 columns (rows live in 16 lanes)
    float sm[4];
#pragma unroll
    for (int r = 0; r < 4; r++) {
      float m = fmaxf(fmaxf(sacc[0][r], sacc[1][r]), fmaxf(sacc[2][r], sacc[3][r]));
      m = fmaxf(m, __shfl_xor(m, 1));
      m = fmaxf(m, __shfl_xor(m, 2));
      m = fmaxf(m, __shfl_xor(m, 4));
      m = fmaxf(m, __shfl_xor(m, 8));
      float s0 = 0.f;
#pragma unroll
      for (int nt = 0; nt < 4; nt++) {
        float e = exp2f((sacc[nt][r] - m) * 1.4426950408889634f);
        sacc[nt][r] = e; s0 += e;
      }
      s0 += __shfl_xor(s0, 1);
      s0 += __shfl_xor(s0, 2);
      s0 += __shfl_xor(s0, 4);
      s0 += __shfl_xor(s0, 8);
      sm[r] = s0;
    }
    // P -> LDS (wave-private rows), layout transform C->A
#pragma unroll
    for (int nt = 0; nt < 4; nt++)
#pragma unroll
      for (int r = 0; r < 4; r++)
        Ps[(trow + r) * 72 + nt * 16 + lane16] = f2bf(sacc[nt][r]);
    // O_h = P V
    fx4 o0 = {0.f, 0.f, 0.f, 0.f}, o1 = {0.f, 0.f, 0.f, 0.f};
#pragma unroll
    for (int ks2 = 0; ks2 < 2; ks2++) {
      const bf16x8 pa = ld8(&Ps[(w * 16 + lane16) * 72 + ks2 * 32 + quad * 8]);
      const bf16x8 v0 = ld8(&VT[(lane16) * 72 + ks2 * 32 + quad * 8]);
      const bf16x8 v1 = ld8(&VT[(16 + lane16) * 72 + ks2 * 32 + quad * 8]);
      o0 = mfma16(pa, v0, o0);
      o1 = mfma16(pa, v1, o1);
    }
    // scale rows by 1/sum, write O into Qs cols [h*32, h*32+32) (already consumed)
#pragma unroll
    for (int r = 0; r < 4; r++) {
      const float inv = 1.0f / sm[r];
      Qs[(trow + r) * 200 + h * 32 + lane16] = f2bf(o0[r] * inv);
      Qs[(trow + r) * 200 + h * 32 + 16 + lane16] = f2bf(o1[r] * inv);
    }
  }
  __syncthreads();   // proj reads O rows written by other waves

  // ---- proj GEMM (n-split): wave w owns nt = w + 4j, j 0..2 ----
  bf16x8 ofr[4][6];
#pragma unroll
  for (int m = 0; m < 4; m++)
#pragma unroll
    for (int k = 0; k < 6; k++)
      ofr[m][k] = ld8(&Qs[(m * 16 + lane16) * 200 + k * 32 + quad * 8]);

  uint16_t* yb = y_attn + (size_t)b * HW_ * C_;
  uint32_t obase[4][4];
#pragma unroll
  for (int m = 0; m < 4; m++)
#pragma unroll
    for (int r = 0; r < 4; r++) {
      const int tok = m * 16 + quad * 4 + r;
      obase[m][r] = (uint32_t)(((wh * 8 + (tok >> 3)) * W_ + ww * 8 + (tok & 7)) * C_);
    }
#pragma unroll
  for (int j = 0; j < 3; j++) {
    const int nt = w + 4 * j;
    const uint16_t* bp = proj_wt + (nt * 16 + lane16) * C_ + quad * 8;
    bf16x8 bfr[6];
#pragma unroll
    for (int k = 0; k < 6; k++) bfr[k] = ld8(bp + k * 32);
    fx4 acc[4];
#pragma unroll
    for (int m = 0; m < 4; m++) acc[m] = fx4{0.f, 0.f, 0.f, 0.f};
#pragma unroll
    for (int k = 0; k < 6; k++)
#pragma unroll
      for (int m = 0; m < 4; m++) acc[m] = mfma16(ofr[m][k], bfr[k], acc[m]);
    const float pb = proj_b[nt * 16 + lane16];
#pragma unroll
    for (int m = 0; m < 4; m++)
#pragma unroll
      for (int r = 0; r < 4; r++)
        yb[obase[m][r] + nt * 16 + lane16] = f2bf(acc[m][r] + pb);
  }
}

// ---------------- K3a: per-slice channel sums of y_attn ----------------
__global__ __launch_bounds__(256) void gap_partial(const uint16_t* __restrict__ y_attn,
                                                   float* __restrict__ part) {
  int wg = blockIdx.x;           // 1024: b = wg>>9, slice = wg&511 (128 tokens)
  int b = wg >> 9, sl = wg & 511;
  int t = threadIdx.x;
  if (t < 192) {
    size_t base = ((size_t)(b * HW_ + sl * 128)) * C_ + t;
    float s = 0.f;
#pragma unroll 8
    for (int r = 0; r < 128; r++) s += bf2f(y_attn[base + (size_t)r * C_]);
    part[wg * 192 + t] = s;
  }
}

// ---------------- K3b: gap -> channel-attention scale s[b][o] ----------------
__global__ __launch_bounds__(768) void ca_s_kernel(const float* __restrict__ part,
                                                   const float* __restrict__ ca_w,
                                                   const float* __restrict__ ca_b,
                                                   float* __restrict__ sbuf) {
  int b = blockIdx.x;
  int t = threadIdx.x;           // 768 threads
  __shared__ float red[768];
  __shared__ float gap[192];
  int g = t / 192, c = t - g * 192;
  float s = 0.f;
#pragma unroll 8
  for (int i = g; i < 512; i += 4) s += part[(b * 512 + i) * 192 + c];
  red[t] = s;
  __syncthreads();
  if (t < 192)
    gap[t] = (red[t] + red[t + 192] + red[t + 384] + red[t + 576]) * (1.0f / 65536.0f);
  __syncthreads();
  if (t < 192) {
    float acc = ca_b[t];
#pragma unroll 8
    for (int c2 = 0; c2 < 192; c2++) acc += gap[c2] * ca_w[t * 192 + c2];
    sbuf[b * 192 + t] = acc;
  }
}

// ---------------- K4: x_new = x + s*y_attn ; LN2 -> token-major bf16 ----------------
__global__ __launch_bounds__(256, 3) void resid_ln2(
    const float* __restrict__ x, const uint16_t* __restrict__ y_attn,
    const float* __restrict__ sbuf, const float* __restrict__ n2w,
    const float* __restrict__ n2b, float* __restrict__ x_new,
    uint16_t* __restrict__ t2) {
  __shared__ __attribute__((aligned(16))) float tile[192 * 66];
  __shared__ float red[512];
  __shared__ float mus[128];
  int wg = blockIdx.x;
  int b = wg >> 10, hw0 = (wg & 1023) << 6;
  int t = threadIdx.x;
#pragma unroll 4
  for (int it = 0; it < 48; it++) {
    int id = it * 256 + t;
    int c = id >> 6, p = id & 63;
    tile[c * 66 + p] = x[(size_t)b * CHW + (size_t)c * HW_ + hw0 + p];
  }
  __syncthreads();
#pragma unroll 4
  for (int it = 0; it < 48; it++) {
    int id = it * 256 + t;
    int p = id / 192, c = id - p * 192;
    float y = bf2f(y_attn[((size_t)(b * HW_ + hw0 + p)) * C_ + c]);
    tile[c * 66 + p] += sbuf[b * 192 + c] * y;
  }
  __syncthreads();
  {
    int p = t & 63, g = t >> 6;
    float s = 0.f, sq = 0.f;
    for (int c = g * 48; c < g * 48 + 48; c++) {
      float v = tile[c * 66 + p];
      s += v; sq += v * v;
    }
    red[g * 64 + p] = s;
    red[256 + g * 64 + p] = sq;
  }
  __syncthreads();
  if (t < 64) {
    float ss = red[t] + red[64 + t] + red[128 + t] + red[192 + t];
    float qq = red[256 + t] + red[320 + t] + red[384 + t] + red[448 + t];
    float m = ss * (1.0f / C_);
    float var = qq * (1.0f / C_) - m * m;
    mus[t] = m;
    mus[64 + t] = rsqrtf(var + 1e-6f);
  }
  __syncthreads();
#pragma unroll 4
  for (int it = 0; it < 48; it++) {
    int id = it * 256 + t;
    int c = id >> 6, p = id & 63;
    x_new[(size_t)b * CHW + (size_t)c * HW_ + hw0 + p] = tile[c * 66 + p];
  }
#pragma unroll 4
  for (int it = 0; it < 48; it++) {
    int id = it * 256 + t;
    int p = id / 192, c = id - p * 192;
    float v = (tile[c * 66 + p] - mus[p]) * mus[64 + p] * n2w[c] + n2b[c];
    t2[((size_t)(b * HW_ + hw0 + p)) * C_ + c] = f2bf(v);
  }
}

// ---------------- K6: MLP (GEMM1+GELU+GEMM2) + final residual, BCHW out ----------------
// n-split: wave w owns nt%4==w; A-frags for all 64 tokens in registers.
__global__ __launch_bounds__(256, 2) void mlp_kernel(
    const uint16_t* __restrict__ t2, const uint16_t* __restrict__ fc1_wt,
    const float* __restrict__ fc1_b, const uint16_t* __restrict__ fc2_wt,
    const float* __restrict__ fc2_b, const float* __restrict__ x_new,
    float* __restrict__ out) {
  __shared__ __attribute__((aligned(16))) char smem[64 * 392 * 2];  // hbuf, later obuf
  uint16_t* hbuf = (uint16_t*)smem;          // [64][392]
  uint16_t* obuf = (uint16_t*)smem;          // [192][68] (aliased after barrier)
  int wg = blockIdx.x;
  int b = wg >> 10, hw0 = (wg & 1023) << 6;
  int t = threadIdx.x;
  int w = t >> 6, l = t & 63;
  int lane16 = l & 15, quad = l >> 4;

  // A frags for all 64 tokens from token-major t2
  bf16x8 afr[4][6];
  const uint16_t* ab = t2 + ((size_t)(b * HW_ + hw0)) * C_;
#pragma unroll
  for (int m = 0; m < 4; m++) {
    const uint16_t* ap = ab + (m * 16 + lane16) * C_ + quad * 8;
#pragma unroll
    for (int k = 0; k < 6; k++) afr[m][k] = ld8(ap + k * 32);
  }

  // GEMM1 + exact GELU -> hbuf; wave owns nt = w + 4j, j 0..5
#pragma unroll
  for (int j = 0; j < 6; j++) {
    const int nt = w + 4 * j;
    const uint16_t* bp = fc1_wt + (nt * 16 + lane16) * C_ + quad * 8;
    bf16x8 bfr[6];
#pragma unroll
    for (int k = 0; k < 6; k++) bfr[k] = ld8(bp + k * 32);
    fx4 acc[4];
#pragma unroll
    for (int m = 0; m < 4; m++) acc[m] = fx4{0.f, 0.f, 0.f, 0.f};
#pragma unroll
    for (int k = 0; k < 6; k++)
#pragma unroll
      for (int m = 0; m < 4; m++) acc[m] = mfma16(afr[m][k], bfr[k], acc[m]);
    const float bias = fc1_b[nt * 16 + lane16];
#pragma unroll
    for (int m = 0; m < 4; m++)
#pragma unroll
      for (int r = 0; r < 4; r++) {
        float v = acc[m][r] + bias;
        float ge = 0.5f * v * (1.0f + erff(v * 0.7071067811865476f));
        hbuf[(m * 16 + quad * 4 + r) * 392 + nt * 16 + lane16] = f2bf(ge);
      }
  }
  __syncthreads();   // hidden features are cross-wave now

  // GEMM2: wave owns nt = w + 4j, j 0..2; hidden A-frags from LDS in 4 k-chunks
  fx4 acc2[3][4];
#pragma unroll
  for (int j = 0; j < 3; j++)
#pragma unroll
    for (int m = 0; m < 4; m++) acc2[j][m] = fx4{0.f, 0.f, 0.f, 0.f};
#pragma unroll
  for (int kc = 0; kc < 4; kc++) {
    bf16x8 ha[4][3];
#pragma unroll
    for (int m = 0; m < 4; m++)
#pragma unroll
      for (int kk = 0; kk < 3; kk++)
        ha[m][kk] = ld8(&hbuf[(m * 16 + lane16) * 392 + kc * 96 + kk * 32 + quad * 8]);
#pragma unroll
    for (int j = 0; j < 3; j++) {
      const int nt = w + 4 * j;
      const uint16_t* bp = fc2_wt + (nt * 16 + lane16) * HID_ + kc * 96 + quad * 8;
#pragma unroll
      for (int kk = 0; kk < 3; kk++) {
        const bf16x8 bb = ld8(bp + kk * 32);
#pragma unroll
        for (int m = 0; m < 4; m++) acc2[j][m] = mfma16(ha[m][kk], bb, acc2[j][m]);
      }
    }
  }
  __syncthreads();   // all hbuf reads done; obuf may alias

  // obuf transposed [c][tok]
#pragma unroll
  for (int j = 0; j < 3; j++) {
    const int nt = w + 4 * j;
    const float bias = fc2_b[nt * 16 + lane16];
#pragma unroll
    for (int m = 0; m < 4; m++) {
      uint2 vv;
      vv.x = pk2(acc2[j][m][0] + bias, acc2[j][m][1] + bias);
      vv.y = pk2(acc2[j][m][2] + bias, acc2[j][m][3] + bias);
      *reinterpret_cast<uint2*>(&obuf[(nt * 16 + lane16) * 68 + m * 16 + quad * 4]) = vv;
    }
  }
  __syncthreads();
  // out = x_new + y2^T (BCHW coalesced)
#pragma unroll 4
  for (int it = 0; it < 48; it++) {
    int id = it * 256 + t;
    int c = id >> 6, p = id & 63;
    size_t gi = (size_t)b * CHW + (size_t)c * HW_ + hw0 + p;
    out[gi] = x_new[gi] + bf2f(obuf[c * 68 + p]);
  }
}

extern "C" void kernel_launch(void* const* d_in, const int* in_sizes, int n_in,
                              void* d_out, int out_size, void* d_ws, size_t ws_size,
                              hipStream_t stream) {
  const float* x      = (const float*)d_in[0];
  const float* n1w    = (const float*)d_in[1];
  const float* n1b    = (const float*)d_in[2];
  const float* qkv_w  = (const float*)d_in[3];
  const float* qkv_b  = (const float*)d_in[4];
  const float* proj_w = (const float*)d_in[5];
  const float* proj_b = (const float*)d_in[6];
  const float* rpb    = (const float*)d_in[7];
  const float* ca_w   = (const float*)d_in[8];
  const float* ca_b   = (const float*)d_in[9];
  const float* n2w    = (const float*)d_in[10];
  const float* n2b    = (const float*)d_in[11];
  const float* fc1_w  = (const float*)d_in[12];
  const float* fc1_b  = (const float*)d_in[13];
  const float* fc2_w  = (const float*)d_in[14];
  const float* fc2_b  = (const float*)d_in[15];
  float* out = (float*)d_out;

  char* ws = (char*)d_ws;
  uint16_t* y_tok   = (uint16_t*)(ws + 0);           // 50331648 B (aliased by t2)
  uint16_t* y_attn  = (uint16_t*)(ws + 50331648);    // 50331648 B
  float*    x_new   = (float*)   (ws + 100663296);   // 100663296 B
  uint16_t* t2      = y_tok;                         // alias (y_tok dead after attn)
  float*    part    = x_new;                         // alias (gap partials die before x_new written)
  float*    mu      = (float*)   (ws + 201326592);   // 524288 B
  float*    rsig    = (float*)   (ws + 201850880);   // 524288 B
  uint16_t* qkv_wt  = (uint16_t*)(ws + 202375168);   // 221184 B
  uint16_t* proj_wt = (uint16_t*)(ws + 202596352);   // 73728 B
  uint16_t* fc1_wt  = (uint16_t*)(ws + 202670080);   // 147456 B
  uint16_t* fc2_wt  = (uint16_t*)(ws + 202817536);   // 147456 B
  float*    rpbb    = (float*)   (ws + 202964992);   // 98304 B
  float*    sbuf    = (float*)   (ws + 203063296);   // 1536 B

  hipLaunchKernelGGL(prep_kernel, dim3(1248), dim3(256), 0, stream,
                     qkv_w, proj_w, fc1_w, fc2_w, rpb, qkv_wt, proj_wt, fc1_wt, fc2_wt, rpbb);
  hipLaunchKernelGGL(ln1_stats, dim3(512), dim3(256), 0, stream, x, mu, rsig);
  hipLaunchKernelGGL(ln1_apply_kernel, dim3(2048), dim3(256), 0, stream,
                     x, mu, rsig, n1w, n1b, y_tok);
  hipLaunchKernelGGL(attn_kernel, dim3(2048), dim3(256), 0, stream,
                     y_tok, qkv_wt, qkv_b, proj_wt, proj_b, rpbb, y_attn);
  hipLaunchKernelGGL(gap_partial, dim3(1024), dim3(256), 0, stream, y_attn, part);
  hipLaunchKernelGGL(ca_s_kernel, dim3(2), dim3(768), 0, stream, part, ca_w, ca_b, sbuf);
  hipLaunchKernelGGL(resid_ln2, dim3(2048), dim3(256), 0, stream,
                     x, y_attn, sbuf, n2w, n2b, x_new, t2);
  hipLaunchKernelGGL(mlp_kernel, dim3(2048), dim3(256), 0, stream,
                     t2, fc1_wt, fc1_b, fc2_wt, fc2_b, x_new, out);
}

// Round 3
// 556.934 us; speedup vs baseline: 1.6797x; 1.0328x over previous
//
#include <hip/hip_runtime.h>
#include <hip/hip_bf16.h>
#include <stdint.h>

#define C_   192
#define H_   256
#define W_   256
#define HW_  65536
#define CHW  12582912
#define NH_  6
#define HID_ 384

typedef __attribute__((ext_vector_type(8))) __bf16 bf16x8;
typedef __attribute__((ext_vector_type(4))) float  fx4;

__device__ __forceinline__ uint16_t f2bf(float f) {
  uint32_t u = __builtin_bit_cast(uint32_t, f);
  u += 0x7fffu + ((u >> 16) & 1u);
  return (uint16_t)(u >> 16);
}
__device__ __forceinline__ float bf2f(uint16_t h) {
  uint32_t u = ((uint32_t)h) << 16;
  return __builtin_bit_cast(float, u);
}
__device__ __forceinline__ uint32_t pk2(float a, float b) {
  return (uint32_t)f2bf(a) | ((uint32_t)f2bf(b) << 16);
}
__device__ __forceinline__ bf16x8 ld8(const uint16_t* p) {
  uint4 v = *reinterpret_cast<const uint4*>(p);
  return __builtin_bit_cast(bf16x8, v);
}
__device__ __forceinline__ fx4 mfma16(bf16x8 a, bf16x8 b, fx4 c) {
  return __builtin_amdgcn_mfma_f32_16x16x32_bf16(a, b, c, 0, 0, 0);
}

// ---------------- K0: weight prep (transpose to bf16 B-fragment layout) ----------------
__global__ __launch_bounds__(256) void prep_kernel(
    const float* __restrict__ qkv_w, const float* __restrict__ proj_w,
    const float* __restrict__ fc1_w, const float* __restrict__ fc2_w,
    const float* __restrict__ rpb,
    uint16_t* __restrict__ qkv_wt, uint16_t* __restrict__ proj_wt,
    uint16_t* __restrict__ fc1_wt, uint16_t* __restrict__ fc2_wt,
    float* __restrict__ rpbb) {
  int tid = blockIdx.x * 256 + threadIdx.x;
  if (tid < 576 * 192) {                       // qkv_wt[f][k] = qkv_w[k][f]
    int f = tid / 192, k = tid % 192;
    qkv_wt[tid] = f2bf(qkv_w[k * 576 + f]);
  }
  int t1 = tid - 576 * 192;
  if (t1 >= 0 && t1 < 192 * 192) {             // proj_wt[f][k]
    int f = t1 / 192, k = t1 % 192;
    proj_wt[t1] = f2bf(proj_w[k * 192 + f]);
  }
  int t2 = t1 - 192 * 192;
  if (t2 >= 0 && t2 < 384 * 192) {             // fc1_wt[f][k]
    int f = t2 / 192, k = t2 % 192;
    fc1_wt[t2] = f2bf(fc1_w[k * 384 + f]);
  }
  int t3 = t2 - 384 * 192;
  if (t3 >= 0 && t3 < 192 * 384) {             // fc2_wt[o][k]
    int f = t3 / 384, k = t3 % 384;
    fc2_wt[t3] = f2bf(fc2_w[k * 192 + f]);
  }
  int t4 = t3 - 192 * 384;
  if (t4 >= 0 && t4 < 6 * 64 * 64) {           // rpbb[h][n][m]
    int h = t4 / 4096, nm = t4 % 4096, n = nm / 64, m = nm % 64;
    int yn = n >> 3, xn = n & 7, ym = m >> 3, xm = m & 7;
    int idx = (yn - ym + 7) * 15 + (xn - xm + 7);
    rpbb[t4] = rpb[idx * NH_ + h];
  }
}

// ---------------- K1a: LN1 stats (mu, rsig per pixel) ----------------
__global__ __launch_bounds__(256) void ln1_stats(const float* __restrict__ x,
                                                 float* __restrict__ mu,
                                                 float* __restrict__ rsig) {
  int t = blockIdx.x * 256 + threadIdx.x;   // (b,hw)
  int b = t >> 16, hw = t & 65535;
  const float* xp = x + (size_t)b * CHW + hw;
  float s = 0.f, sq = 0.f;
#pragma unroll 8
  for (int c = 0; c < C_; c++) {
    float v = xp[(size_t)c * HW_];
    s += v; sq += v * v;
  }
  float m = s * (1.0f / C_);
  float var = sq * (1.0f / C_) - m * m;
  mu[t] = m;
  rsig[t] = rsqrtf(var + 1e-6f);
}

// ---------------- K1b: apply LN1 + roll-reinterpret shuffle + transpose -> token-major bf16 --
__global__ __launch_bounds__(256) void ln1_apply_kernel(
    const float* __restrict__ x, const float* __restrict__ mu, const float* __restrict__ rsig,
    const float* __restrict__ n1w, const float* __restrict__ n1b,
    uint16_t* __restrict__ y_tok) {
  __shared__ __attribute__((aligned(16))) uint16_t tile[192 * 66];
  int wg = blockIdx.x;
  int b = wg >> 10, hw0 = (wg & 1023) << 6;
  int t = threadIdx.x;
  const float* xb = x + (size_t)b * CHW;
  const float* mub = mu + b * HW_;
  const float* rsb = rsig + b * HW_;
#pragma unroll 4
  for (int it = 0; it < 48; it++) {
    int id = it * 256 + t;
    int ca = id >> 6, pp = id & 63;
    int g = ca * 65536 + hw0 + pp;
    int h2 = g / 49152;
    int r = g - h2 * 49152;
    int w2 = r / 192;
    int c2 = r - w2 * 192;
    int f = ((h2 + 4) & 255) * 49152 + ((w2 + 4) & 255) * 192 + c2;
    int cnat = f >> 16;
    int hwn = f & 65535;
    float v = (xb[f] - mub[hwn]) * rsb[hwn] * n1w[cnat] + n1b[cnat];
    tile[ca * 66 + pp] = f2bf(v);
  }
  __syncthreads();
  uint16_t* yb = y_tok + ((size_t)(b * HW_ + hw0)) * C_;
#pragma unroll 4
  for (int it = 0; it < 48; it++) {
    int id = it * 256 + t;
    int pp = id / 192, ca = id - pp * 192;
    yb[id] = tile[ca * 66 + pp];
  }
}

// ---------------- K2: fused window attention + fused GAP partials ----------------
// n-split GEMMs: each wave holds A-frags for all 64 tokens, owns n-tiles nt%4==w.
__global__ __launch_bounds__(256, 2) void attn_kernel(
    const uint16_t* __restrict__ y_tok, const uint16_t* __restrict__ qkv_wt,
    const float* __restrict__ qkv_b, const uint16_t* __restrict__ proj_wt,
    const float* __restrict__ proj_b, const float* __restrict__ rpbb,
    uint16_t* __restrict__ y_attn, float* __restrict__ part) {
  __shared__ __attribute__((aligned(16))) uint16_t Qs[64 * 200]; // Q, later O
  __shared__ __attribute__((aligned(16))) uint16_t Ks[64 * 200];
  __shared__ __attribute__((aligned(16))) uint16_t VT[32 * 72];
  __shared__ __attribute__((aligned(16))) uint16_t Ps[64 * 72];
  const int wg = blockIdx.x;
  const int b = wg >> 10, wid = wg & 1023;
  const int wh = wid >> 5, ww = wid & 31;
  const int t = threadIdx.x;
  const int w = t >> 6, l = t & 63;
  const int lane16 = l & 15, quad = l >> 4;
  const int trow = w * 16 + quad * 4;

  // A fragments for ALL 64 tokens (token rows contiguous 384B in y_tok)
  bf16x8 afr[4][6];
#pragma unroll
  for (int m = 0; m < 4; m++) {
    const int tok = m * 16 + lane16;
    const uint16_t* ap = y_tok +
        ((size_t)(b * HW_ + (wh * 8 + (tok >> 3)) * W_ + ww * 8 + (tok & 7))) * C_ + quad * 8;
#pragma unroll
    for (int k = 0; k < 6; k++) afr[m][k] = ld8(ap + k * 32);
  }

  const float scale = 0.17677669529663687f;
  uint32_t vpack[3][4][2];

  // ---- QKV GEMM: wave w owns nt = w + 4j. j 0..2: Q, 3..5: K, 6..8: V ----
#pragma unroll
  for (int j = 0; j < 3; j++) {
    const int nt = w + 4 * j;
    const uint16_t* bp = qkv_wt + (nt * 16 + lane16) * C_ + quad * 8;
    bf16x8 bfr[6];
#pragma unroll
    for (int k = 0; k < 6; k++) bfr[k] = ld8(bp + k * 32);
    fx4 acc[4];
#pragma unroll
    for (int m = 0; m < 4; m++) acc[m] = fx4{0.f, 0.f, 0.f, 0.f};
#pragma unroll
    for (int k = 0; k < 6; k++)
#pragma unroll
      for (int m = 0; m < 4; m++) acc[m] = mfma16(afr[m][k], bfr[k], acc[m]);
    const int f = nt * 16 + lane16;
    const float bias = qkv_b[f];
#pragma unroll
    for (int m = 0; m < 4; m++)
#pragma unroll
      for (int r = 0; r < 4; r++)
        Qs[(m * 16 + quad * 4 + r) * 200 + f] = f2bf((acc[m][r] + bias) * scale);
  }
#pragma unroll
  for (int j = 3; j < 6; j++) {
    const int nt = w + 4 * j;
    const uint16_t* bp = qkv_wt + (nt * 16 + lane16) * C_ + quad * 8;
    bf16x8 bfr[6];
#pragma unroll
    for (int k = 0; k < 6; k++) bfr[k] = ld8(bp + k * 32);
    fx4 acc[4];
#pragma unroll
    for (int m = 0; m < 4; m++) acc[m] = fx4{0.f, 0.f, 0.f, 0.f};
#pragma unroll
    for (int k = 0; k < 6; k++)
#pragma unroll
      for (int m = 0; m < 4; m++) acc[m] = mfma16(afr[m][k], bfr[k], acc[m]);
    const int f = nt * 16 + lane16;
    const float bias = qkv_b[f];
#pragma unroll
    for (int m = 0; m < 4; m++)
#pragma unroll
      for (int r = 0; r < 4; r++)
        Ks[(m * 16 + quad * 4 + r) * 200 + (f - 192)] = f2bf(acc[m][r] + bias);
  }
#pragma unroll
  for (int j = 6; j < 9; j++) {
    const int nt = w + 4 * j;
    const uint16_t* bp = qkv_wt + (nt * 16 + lane16) * C_ + quad * 8;
    bf16x8 bfr[6];
#pragma unroll
    for (int k = 0; k < 6; k++) bfr[k] = ld8(bp + k * 32);
    fx4 acc[4];
#pragma unroll
    for (int m = 0; m < 4; m++) acc[m] = fx4{0.f, 0.f, 0.f, 0.f};
#pragma unroll
    for (int k = 0; k < 6; k++)
#pragma unroll
      for (int m = 0; m < 4; m++) acc[m] = mfma16(afr[m][k], bfr[k], acc[m]);
    const float bias = qkv_b[nt * 16 + lane16];
    const int jv = j - 6;   // owned V-tile vt = w + 4*jv  (vt%4 == w)
#pragma unroll
    for (int m = 0; m < 4; m++) {
      vpack[jv][m][0] = pk2(acc[m][0] + bias, acc[m][1] + bias);
      vpack[jv][m][1] = pk2(acc[m][2] + bias, acc[m][3] + bias);
    }
  }

  const bool whe = (wh == 31), wwe = (ww == 31);

  for (int h = 0; h < 6; h++) {
    __syncthreads();  // Q/K ready (h=0) / prev-head PV reads of VT done (h>0)
    // stage V-tiles 2h, 2h+1 from their owning waves
    {
      const int vt0 = 2 * h, vt1 = 2 * h + 1;
      if (w == (vt0 & 3)) {
        const int jv = vt0 >> 2;
#pragma unroll
        for (int m = 0; m < 4; m++) {
          uint2 vv; vv.x = vpack[jv][m][0]; vv.y = vpack[jv][m][1];
          *reinterpret_cast<uint2*>(&VT[lane16 * 72 + m * 16 + quad * 4]) = vv;
        }
      }
      if (w == (vt1 & 3)) {
        const int jv = vt1 >> 2;
#pragma unroll
        for (int m = 0; m < 4; m++) {
          uint2 vv; vv.x = vpack[jv][m][0]; vv.y = vpack[jv][m][1];
          *reinterpret_cast<uint2*>(&VT[(16 + lane16) * 72 + m * 16 + quad * 4]) = vv;
        }
      }
    }
    __syncthreads();

    // S = Q K^T (one K=32 step per head)
    const bf16x8 qa = ld8(&Qs[(w * 16 + lane16) * 200 + h * 32 + quad * 8]);
    fx4 sacc[4];
#pragma unroll
    for (int nt = 0; nt < 4; nt++) {
      const bf16x8 kb = ld8(&Ks[(nt * 16 + lane16) * 200 + h * 32 + quad * 8]);
      fx4 z = {0.f, 0.f, 0.f, 0.f};
      sacc[nt] = mfma16(qa, kb, z);
    }
    // bias + shifted-window mask
    const float* rb = rpbb + h * 4096;
#pragma unroll
    for (int nt = 0; nt < 4; nt++) {
      const int ct = nt * 16 + lane16;
      const bool rbc = whe && ((ct >> 3) >= 4);
      const bool cbc = wwe && ((ct & 7) >= 4);
#pragma unroll
      for (int r = 0; r < 4; r++) {
        const int rt = trow + r;
        const bool rbr = whe && ((rt >> 3) >= 4);
        const bool cbr = wwe && ((rt & 7) >= 4);
        float v = sacc[nt][r] + rb[rt * 64 + ct];
        if (rbr != rbc || cbr != cbc) v -= 100.f;
        sacc[nt][r] = v;
      }
    }
    // softmax across the 64 columns (rows live in 16 lanes)
    float sm[4];
#pragma unroll
    for (int r = 0; r < 4; r++) {
      float m = fmaxf(fmaxf(sacc[0][r], sacc[1][r]), fmaxf(sacc[2][r], sacc[3][r]));
      m = fmaxf(m, __shfl_xor(m, 1));
      m = fmaxf(m, __shfl_xor(m, 2));
      m = fmaxf(m, __shfl_xor(m, 4));
      m = fmaxf(m, __shfl_xor(m, 8));
      float s0 = 0.f;
#pragma unroll
      for (int nt = 0; nt < 4; nt++) {
        float e = exp2f((sacc[nt][r] - m) * 1.4426950408889634f);
        sacc[nt][r] = e; s0 += e;
      }
      s0 += __shfl_xor(s0, 1);
      s0 += __shfl_xor(s0, 2);
      s0 += __shfl_xor(s0, 4);
      s0 += __shfl_xor(s0, 8);
      sm[r] = s0;
    }
    // P -> LDS (wave-private rows), layout transform C->A
#pragma unroll
    for (int nt = 0; nt < 4; nt++)
#pragma unroll
      for (int r = 0; r < 4; r++)
        Ps[(trow + r) * 72 + nt * 16 + lane16] = f2bf(sacc[nt][r]);
    // O_h = P V
    fx4 o0 = {0.f, 0.f, 0.f, 0.f}, o1 = {0.f, 0.f, 0.f, 0.f};
#pragma unroll
    for (int ks2 = 0; ks2 < 2; ks2++) {
      const bf16x8 pa = ld8(&Ps[(w * 16 + lane16) * 72 + ks2 * 32 + quad * 8]);
      const bf16x8 v0 = ld8(&VT[(lane16) * 72 + ks2 * 32 + quad * 8]);
      const bf16x8 v1 = ld8(&VT[(16 + lane16) * 72 + ks2 * 32 + quad * 8]);
      o0 = mfma16(pa, v0, o0);
      o1 = mfma16(pa, v1, o1);
    }
    // scale rows by 1/sum, write O into Qs cols [h*32, h*32+32) (already consumed)
#pragma unroll
    for (int r = 0; r < 4; r++) {
      const float inv = 1.0f / sm[r];
      Qs[(trow + r) * 200 + h * 32 + lane16] = f2bf(o0[r] * inv);
      Qs[(trow + r) * 200 + h * 32 + 16 + lane16] = f2bf(o1[r] * inv);
    }
  }
  __syncthreads();   // proj reads O rows written by other waves

  // ---- proj GEMM (n-split): wave w owns nt = w + 4j, j 0..2 ----
  bf16x8 ofr[4][6];
#pragma unroll
  for (int m = 0; m < 4; m++)
#pragma unroll
    for (int k = 0; k < 6; k++)
      ofr[m][k] = ld8(&Qs[(m * 16 + lane16) * 200 + k * 32 + quad * 8]);

  uint16_t* yb = y_attn + (size_t)b * HW_ * C_;
  uint32_t obase[4][4];
#pragma unroll
  for (int m = 0; m < 4; m++)
#pragma unroll
    for (int r = 0; r < 4; r++) {
      const int tok = m * 16 + quad * 4 + r;
      obase[m][r] = (uint32_t)(((wh * 8 + (tok >> 3)) * W_ + ww * 8 + (tok & 7)) * C_);
    }
#pragma unroll
  for (int j = 0; j < 3; j++) {
    const int nt = w + 4 * j;
    const uint16_t* bp = proj_wt + (nt * 16 + lane16) * C_ + quad * 8;
    bf16x8 bfr[6];
#pragma unroll
    for (int k = 0; k < 6; k++) bfr[k] = ld8(bp + k * 32);
    fx4 acc[4];
#pragma unroll
    for (int m = 0; m < 4; m++) acc[m] = fx4{0.f, 0.f, 0.f, 0.f};
#pragma unroll
    for (int k = 0; k < 6; k++)
#pragma unroll
      for (int m = 0; m < 4; m++) acc[m] = mfma16(ofr[m][k], bfr[k], acc[m]);
    const float pb = proj_b[nt * 16 + lane16];
    float cs = 0.f;   // per-lane channel partial sum (GAP fusion)
#pragma unroll
    for (int m = 0; m < 4; m++)
#pragma unroll
      for (int r = 0; r < 4; r++) {
        const float v = acc[m][r] + pb;
        yb[obase[m][r] + nt * 16 + lane16] = f2bf(v);
        cs += v;
      }
    // quads hold disjoint tokens, same channel -> sum across quads
    cs += __shfl_xor(cs, 16);
    cs += __shfl_xor(cs, 32);
    if (l < 16) part[(size_t)wg * 192 + nt * 16 + lane16] = cs;
  }
}

// ---------------- K3: gap reduce + channel-attention scale s[b][o] ----------------
__global__ __launch_bounds__(768) void ca_s_kernel(const float* __restrict__ part,
                                                   const float* __restrict__ ca_w,
                                                   const float* __restrict__ ca_b,
                                                   float* __restrict__ sbuf) {
  int b = blockIdx.x;
  int t = threadIdx.x;           // 768 threads
  __shared__ float red[768];
  __shared__ float gap[192];
  int g = t / 192, c = t - g * 192;
  float s = 0.f;
#pragma unroll 8
  for (int i = g; i < 1024; i += 4) s += part[((size_t)b * 1024 + i) * 192 + c];
  red[t] = s;
  __syncthreads();
  if (t < 192)
    gap[t] = (red[t] + red[t + 192] + red[t + 384] + red[t + 576]) * (1.0f / 65536.0f);
  __syncthreads();
  if (t < 192) {
    float acc = ca_b[t];
#pragma unroll 8
    for (int c2 = 0; c2 < 192; c2++) acc += gap[c2] * ca_w[t * 192 + c2];
    sbuf[b * 192 + t] = acc;
  }
}

// ---------------- K4: resid + LN2 -> token-major bf16 t2 (no x_new write) ----------------
__global__ __launch_bounds__(256, 3) void resid_ln2(
    const float* __restrict__ x, const uint16_t* __restrict__ y_attn,
    const float* __restrict__ sbuf, const float* __restrict__ n2w,
    const float* __restrict__ n2b, uint16_t* __restrict__ t2) {
  __shared__ __attribute__((aligned(16))) float tile[192 * 66];
  __shared__ float red[512];
  __shared__ float mus[128];
  int wg = blockIdx.x;
  int b = wg >> 10, hw0 = (wg & 1023) << 6;
  int t = threadIdx.x;
#pragma unroll 4
  for (int it = 0; it < 48; it++) {
    int id = it * 256 + t;
    int c = id >> 6, p = id & 63;
    tile[c * 66 + p] = x[(size_t)b * CHW + (size_t)c * HW_ + hw0 + p];
  }
  __syncthreads();
#pragma unroll 4
  for (int it = 0; it < 48; it++) {
    int id = it * 256 + t;
    int p = id / 192, c = id - p * 192;
    float y = bf2f(y_attn[((size_t)(b * HW_ + hw0 + p)) * C_ + c]);
    tile[c * 66 + p] += sbuf[b * 192 + c] * y;
  }
  __syncthreads();
  {
    int p = t & 63, g = t >> 6;
    float s = 0.f, sq = 0.f;
    for (int c = g * 48; c < g * 48 + 48; c++) {
      float v = tile[c * 66 + p];
      s += v; sq += v * v;
    }
    red[g * 64 + p] = s;
    red[256 + g * 64 + p] = sq;
  }
  __syncthreads();
  if (t < 64) {
    float ss = red[t] + red[64 + t] + red[128 + t] + red[192 + t];
    float qq = red[256 + t] + red[320 + t] + red[384 + t] + red[448 + t];
    float m = ss * (1.0f / C_);
    float var = qq * (1.0f / C_) - m * m;
    mus[t] = m;
    mus[64 + t] = rsqrtf(var + 1e-6f);
  }
  __syncthreads();
#pragma unroll 4
  for (int it = 0; it < 48; it++) {
    int id = it * 256 + t;
    int p = id / 192, c = id - p * 192;
    float v = (tile[c * 66 + p] - mus[p]) * mus[64 + p] * n2w[c] + n2b[c];
    t2[((size_t)(b * HW_ + hw0 + p)) * C_ + c] = f2bf(v);
  }
}

// ---------------- K5: MLP + recomputed residual -> out (BCHW f32) ----------------
// n-split; epilogue: y2 -> ftile(f32), += s*y_attn (c-fast), out = x + ftile (p-fast).
__global__ __launch_bounds__(256, 3) void mlp_kernel(
    const uint16_t* __restrict__ t2, const uint16_t* __restrict__ fc1_wt,
    const float* __restrict__ fc1_b, const uint16_t* __restrict__ fc2_wt,
    const float* __restrict__ fc2_b, const float* __restrict__ x,
    const uint16_t* __restrict__ y_attn, const float* __restrict__ sbuf,
    float* __restrict__ out) {
  __shared__ __attribute__((aligned(16))) char smem[192 * 66 * 4];  // hbuf | ftile
  __shared__ float sarr[192];
  uint16_t* hbuf = (uint16_t*)smem;          // [64][392] bf16
  float* ftile = (float*)smem;               // [192][66] f32 (aliased after barrier)
  int wg = blockIdx.x;
  int b = wg >> 10, hw0 = (wg & 1023) << 6;
  int t = threadIdx.x;
  int w = t >> 6, l = t & 63;
  int lane16 = l & 15, quad = l >> 4;
  if (t < 192) sarr[t] = sbuf[b * 192 + t];

  // A frags for all 64 tokens from token-major t2
  bf16x8 afr[4][6];
  const uint16_t* ab = t2 + ((size_t)(b * HW_ + hw0)) * C_;
#pragma unroll
  for (int m = 0; m < 4; m++) {
    const uint16_t* ap = ab + (m * 16 + lane16) * C_ + quad * 8;
#pragma unroll
    for (int k = 0; k < 6; k++) afr[m][k] = ld8(ap + k * 32);
  }

  // GEMM1 + exact GELU -> hbuf; wave owns nt = w + 4j, j 0..5
#pragma unroll
  for (int j = 0; j < 6; j++) {
    const int nt = w + 4 * j;
    const uint16_t* bp = fc1_wt + (nt * 16 + lane16) * C_ + quad * 8;
    bf16x8 bfr[6];
#pragma unroll
    for (int k = 0; k < 6; k++) bfr[k] = ld8(bp + k * 32);
    fx4 acc[4];
#pragma unroll
    for (int m = 0; m < 4; m++) acc[m] = fx4{0.f, 0.f, 0.f, 0.f};
#pragma unroll
    for (int k = 0; k < 6; k++)
#pragma unroll
      for (int m = 0; m < 4; m++) acc[m] = mfma16(afr[m][k], bfr[k], acc[m]);
    const float bias = fc1_b[nt * 16 + lane16];
#pragma unroll
    for (int m = 0; m < 4; m++)
#pragma unroll
      for (int r = 0; r < 4; r++) {
        float v = acc[m][r] + bias;
        float ge = 0.5f * v * (1.0f + erff(v * 0.7071067811865476f));
        hbuf[(m * 16 + quad * 4 + r) * 392 + nt * 16 + lane16] = f2bf(ge);
      }
  }
  __syncthreads();   // hidden features are cross-wave now

  // GEMM2: wave owns nt = w + 4j, j 0..2; hidden A-frags from LDS in 4 k-chunks
  fx4 acc2[3][4];
#pragma unroll
  for (int j = 0; j < 3; j++)
#pragma unroll
    for (int m = 0; m < 4; m++) acc2[j][m] = fx4{0.f, 0.f, 0.f, 0.f};
#pragma unroll
  for (int kc = 0; kc < 4; kc++) {
    bf16x8 ha[4][3];
#pragma unroll
    for (int m = 0; m < 4; m++)
#pragma unroll
      for (int kk = 0; kk < 3; kk++)
        ha[m][kk] = ld8(&hbuf[(m * 16 + lane16) * 392 + kc * 96 + kk * 32 + quad * 8]);
#pragma unroll
    for (int j = 0; j < 3; j++) {
      const int nt = w + 4 * j;
      const uint16_t* bp = fc2_wt + (nt * 16 + lane16) * HID_ + kc * 96 + quad * 8;
#pragma unroll
      for (int kk = 0; kk < 3; kk++) {
        const bf16x8 bb = ld8(bp + kk * 32);
#pragma unroll
        for (int m = 0; m < 4; m++) acc2[j][m] = mfma16(ha[m][kk], bb, acc2[j][m]);
      }
    }
  }
  __syncthreads();   // all hbuf reads done; ftile may alias

  // y2 + bias -> ftile[c][tok] (f32)
#pragma unroll
  for (int j = 0; j < 3; j++) {
    const int nt = w + 4 * j;
    const float bias = fc2_b[nt * 16 + lane16];
#pragma unroll
    for (int m = 0; m < 4; m++) {
      float* fp = &ftile[(nt * 16 + lane16) * 66 + m * 16 + quad * 4];
      float2 a = {acc2[j][m][0] + bias, acc2[j][m][1] + bias};
      float2 b2 = {acc2[j][m][2] + bias, acc2[j][m][3] + bias};
      *reinterpret_cast<float2*>(fp) = a;
      *reinterpret_cast<float2*>(fp + 2) = b2;
    }
  }
  __syncthreads();
  // += s[c] * y_attn (coalesced token-major read)
#pragma unroll 4
  for (int it = 0; it < 48; it++) {
    int id = it * 256 + t;
    int p = id / 192, c = id - p * 192;
    float y = bf2f(y_attn[((size_t)(b * HW_ + hw0 + p)) * C_ + c]);
    ftile[c * 66 + p] += sarr[c] * y;
  }
  __syncthreads();
  // out = x + ftile (BCHW coalesced)
#pragma unroll 4
  for (int it = 0; it < 48; it++) {
    int id = it * 256 + t;
    int c = id >> 6, p = id & 63;
    size_t gi = (size_t)b * CHW + (size_t)c * HW_ + hw0 + p;
    out[gi] = x[gi] + ftile[c * 66 + p];
  }
}

extern "C" void kernel_launch(void* const* d_in, const int* in_sizes, int n_in,
                              void* d_out, int out_size, void* d_ws, size_t ws_size,
                              hipStream_t stream) {
  const float* x      = (const float*)d_in[0];
  const float* n1w    = (const float*)d_in[1];
  const float* n1b    = (const float*)d_in[2];
  const float* qkv_w  = (const float*)d_in[3];
  const float* qkv_b  = (const float*)d_in[4];
  const float* proj_w = (const float*)d_in[5];
  const float* proj_b = (const float*)d_in[6];
  const float* rpb    = (const float*)d_in[7];
  const float* ca_w   = (const float*)d_in[8];
  const float* ca_b   = (const float*)d_in[9];
  const float* n2w    = (const float*)d_in[10];
  const float* n2b    = (const float*)d_in[11];
  const float* fc1_w  = (const float*)d_in[12];
  const float* fc1_b  = (const float*)d_in[13];
  const float* fc2_w  = (const float*)d_in[14];
  const float* fc2_b  = (const float*)d_in[15];
  float* out = (float*)d_out;

  char* ws = (char*)d_ws;
  uint16_t* y_tok   = (uint16_t*)(ws + 0);           // 50331648 B (aliased by t2)
  uint16_t* y_attn  = (uint16_t*)(ws + 50331648);    // 50331648 B
  uint16_t* t2      = y_tok;                         // alias (y_tok dead after attn)
  float*    mu      = (float*)   (ws + 100663296);   // 524288 B
  float*    rsig    = (float*)   (ws + 101187584);   // 524288 B
  uint16_t* qkv_wt  = (uint16_t*)(ws + 101711872);   // 221184 B
  uint16_t* proj_wt = (uint16_t*)(ws + 101933056);   // 73728 B
  uint16_t* fc1_wt  = (uint16_t*)(ws + 102006784);   // 147456 B
  uint16_t* fc2_wt  = (uint16_t*)(ws + 102154240);   // 147456 B
  float*    rpbb    = (float*)   (ws + 102301696);   // 98304 B
  float*    part    = (float*)   (ws + 102400000);   // 1572864 B
  float*    sbuf    = (float*)   (ws + 103972864);   // 1536 B

  hipLaunchKernelGGL(prep_kernel, dim3(1248), dim3(256), 0, stream,
                     qkv_w, proj_w, fc1_w, fc2_w, rpb, qkv_wt, proj_wt, fc1_wt, fc2_wt, rpbb);
  hipLaunchKernelGGL(ln1_stats, dim3(512), dim3(256), 0, stream, x, mu, rsig);
  hipLaunchKernelGGL(ln1_apply_kernel, dim3(2048), dim3(256), 0, stream,
                     x, mu, rsig, n1w, n1b, y_tok);
  hipLaunchKernelGGL(attn_kernel, dim3(2048), dim3(256), 0, stream,
                     y_tok, qkv_wt, qkv_b, proj_wt, proj_b, rpbb, y_attn, part);
  hipLaunchKernelGGL(ca_s_kernel, dim3(2), dim3(768), 0, stream, part, ca_w, ca_b, sbuf);
  hipLaunchKernelGGL(resid_ln2, dim3(2048), dim3(256), 0, stream,
                     x, y_attn, sbuf, n2w, n2b, t2);
  hipLaunchKernelGGL(mlp_kernel, dim3(2048), dim3(256), 0, stream,
                     t2, fc1_wt, fc1_b, fc2_wt, fc2_b, x, y_attn, sbuf, out);
}